// Round 11
// baseline (6827.847 us; speedup 1.0000x reference)
//
#include <hip/hip_runtime.h>

#define V 256
#define H 2048
#define A 512
#define S 512
#define NBLK 128
#define NTHR 512
#define CH 64            // floats per chunk slot (256B spread)
#define HPH (512*CH)     // h-exchange floats per phase (512 x 16B chunks)
#define DPH (128*CH)     // dp/e-exchange floats per phase (128 x 16B chunks)
#define SENTU 0x7FC00000u
#define SENT64 0x7FC000007FC00000ULL

typedef float f32x4 __attribute__((ext_vector_type(4)));
typedef float f32x2 __attribute__((ext_vector_type(2)));
typedef unsigned long long u64;

// ---- plain coherent poll side (NaN-sentinel self-tagging) ----
__device__ __forceinline__ f32x4 ld_cg4(const float* p) {
    f32x4 r;
    asm volatile("global_load_dwordx4 %0, %1, off sc0 sc1\n\ts_waitcnt vmcnt(0)"
                 : "=&v"(r) : "v"(p) : "memory");
    return r;
}
__device__ __forceinline__ f32x4 poll4(const float* p) {
    f32x4 r = ld_cg4(p);
    while (__float_as_uint(r.x) == SENTU || __float_as_uint(r.y) == SENTU ||
           __float_as_uint(r.z) == SENTU || __float_as_uint(r.w) == SENTU)
        r = ld_cg4(p);
    return r;
}

// ---- atomic publish side: exchange executes at the IC coherence point ----
__device__ __forceinline__ void vm_drain() { asm volatile("s_waitcnt vmcnt(0)" ::: "memory"); }
__device__ __forceinline__ void ax_st64(u64* p, u64 v) {
    (void)__hip_atomic_exchange(p, v, __ATOMIC_RELAXED, __HIP_MEMORY_SCOPE_AGENT);
}
__device__ __forceinline__ void ax_st32(unsigned* p, unsigned v) {
    (void)__hip_atomic_exchange(p, v, __ATOMIC_RELAXED, __HIP_MEMORY_SCOPE_AGENT);
}
__device__ __forceinline__ u64 pack2(float a, float b) {
    return ((u64)__float_as_uint(b) << 32) | (u64)__float_as_uint(a);
}

// ---- plain resets (2-step slack covers visibility; ordered into next publish by vm_drain) ----
__device__ __forceinline__ void st_rst2(float* p) {
    f32x2 v; v.x = __uint_as_float(SENTU); v.y = __uint_as_float(SENTU);
    asm volatile("global_store_dwordx2 %0, %1, off sc0 sc1" :: "v"(p), "v"(v) : "memory");
}
__device__ __forceinline__ void st_rst1(float* p) {
    float v = __uint_as_float(SENTU);
    asm volatile("global_store_dword %0, %1, off sc0 sc1" :: "v"(p), "v"(v) : "memory");
}

__global__ void init_ex(unsigned* p, int n) {
    int i = blockIdx.x * blockDim.x + threadIdx.x;
    if (i < n) p[i] = SENTU;
}

// ---------------- generic NT GEMM (unchanged) ----------------
__global__ __launch_bounds__(256) void gemm_nt(
    const float* __restrict__ Amat, int lda,
    const float* __restrict__ Bmat, int ldb,
    float* __restrict__ C, int ldc,
    const float* __restrict__ bias, int M, int N, int K)
{
    __shared__ float As[16][68];
    __shared__ float Bs[16][68];
    const int tid = threadIdx.x;
    const int tx = tid & 15;
    const int ty = tid >> 4;
    const int m0 = blockIdx.y * 64;
    const int n0 = blockIdx.x * 64;
    const int lr = tid >> 2;
    const int lk = (tid & 3) * 4;

    float acc[4][4] = {};
    for (int k0 = 0; k0 < K; k0 += 16) {
        float4 av = *(const float4*)(Amat + (size_t)(m0 + lr) * lda + k0 + lk);
        float4 bv = *(const float4*)(Bmat + (size_t)(n0 + lr) * ldb + k0 + lk);
        __syncthreads();
        As[lk+0][lr] = av.x; As[lk+1][lr] = av.y; As[lk+2][lr] = av.z; As[lk+3][lr] = av.w;
        Bs[lk+0][lr] = bv.x; Bs[lk+1][lr] = bv.y; Bs[lk+2][lr] = bv.z; Bs[lk+3][lr] = bv.w;
        __syncthreads();
        #pragma unroll
        for (int k = 0; k < 16; ++k) {
            float a4[4], b4[4];
            #pragma unroll
            for (int i = 0; i < 4; ++i) a4[i] = As[k][ty*4+i];
            #pragma unroll
            for (int j = 0; j < 4; ++j) b4[j] = Bs[k][tx*4+j];
            #pragma unroll
            for (int i = 0; i < 4; ++i)
                #pragma unroll
                for (int j = 0; j < 4; ++j) acc[i][j] += a4[i] * b4[j];
        }
    }
    #pragma unroll
    for (int i = 0; i < 4; ++i) {
        const int m = m0 + ty*4 + i;
        #pragma unroll
        for (int j = 0; j < 4; ++j) {
            const int n = n0 + tx*4 + j;
            float v = acc[i][j];
            if (bias) v += bias[n];
            C[(size_t)m * ldc + n] = v;
        }
    }
}

// ---------------- persistent encoder scan: atomic publish, plain poll, double-buffered LDS ----------------
__global__ __launch_bounds__(NTHR, 2) void enc_scan(
    const float* __restrict__ W_enc, const float* __restrict__ accx,
    float* __restrict__ states, float* __restrict__ hex)
{
    __shared__ __align__(16) float hs[2][H];
    const int tid = threadIdx.x;
    const int wid = tid >> 6, lane = tid & 63;
    const int w   = blockIdx.x * 8 + wid;     // 0..1023, rows 2w,2w+1
    const int r0  = 2*w, r1 = r0 + 1;
    const int slot = (w >> 1)*CH + (w & 1)*2; // 8B half of 16B chunk (w>>1)

    f32x4 we0[8], we1[8];
    #pragma unroll
    for (int k = 0; k < 8; ++k) {
        we0[k] = *(const f32x4*)(W_enc + (size_t)r0*(V+H) + V + 4*(lane + 64*k));
        we1[k] = *(const f32x4*)(W_enc + (size_t)r1*(V+H) + V + 4*(lane + 64*k));
    }

    // t = 0
    if (lane == 0) {
        float h0 = tanhf(accx[r0]), h1 = tanhf(accx[r1]);
        vm_drain();
        ax_st64((u64*)(hex + 0*HPH + slot), pack2(h0, h1));
        states[r0] = h0; states[r1] = h1;
    }

    for (int t = 1; t < S; ++t) {
        float ax0 = accx[(size_t)t*H + r0];   // broadcast L2-hit loads, all lanes
        float ax1 = accx[(size_t)t*H + r1];
        ((f32x4*)hs[t&1])[tid] = poll4(hex + ((t-1)%3)*HPH + tid*CH);
        __syncthreads();
        // reset phase (t+1)%3 (proven consumed); drains during the dot
        if (lane == 0) st_rst2(hex + ((t+1)%3)*HPH + slot);

        const f32x4* h4 = (const f32x4*)hs[t&1];
        float a0 = 0.f, a1 = 0.f;
        #pragma unroll
        for (int k = 0; k < 8; ++k) {
            f32x4 hv = h4[lane + 64*k];
            a0 += we0[k].x*hv.x + we0[k].y*hv.y + we0[k].z*hv.z + we0[k].w*hv.w;
            a1 += we1[k].x*hv.x + we1[k].y*hv.y + we1[k].z*hv.z + we1[k].w*hv.w;
        }
        #pragma unroll
        for (int off = 32; off; off >>= 1) { a0 += __shfl_down(a0, off); a1 += __shfl_down(a1, off); }
        if (lane == 0) {
            float h0 = tanhf(a0 + ax0);
            float h1 = tanhf(a1 + ax1);
            vm_drain();                                      // reset at IC before publish
            ax_st64((u64*)(hex + (t%3)*HPH + slot), pack2(h0, h1));
            states[(size_t)t*H + r0] = h0;                   // off critical path
            states[(size_t)t*H + r1] = h1;
        }
    }
}

// ---------------- persistent decoder scan: R7 structure, atomic publishes ----------------
__global__ __launch_bounds__(NTHR, 2) void dec_scan(
    const float* __restrict__ Wa_dec, const float* __restrict__ W_dec,
    const float* __restrict__ enc_proj, const float* __restrict__ v_a,
    const float* __restrict__ WcT, const float* __restrict__ accx,
    const float* __restrict__ enc_states, float* __restrict__ h_dec,
    float* __restrict__ hexd, float* __restrict__ dpex, float* __restrict__ eex)
{
    __shared__ __align__(16) float hs[2][H];
    __shared__ __align__(16) float ps[A];
    __shared__ __align__(16) float es[S];
    __shared__ float zred[8];
    const int tid = threadIdx.x;
    const int wid = tid >> 6, lane = tid & 63;
    const int w   = blockIdx.x * 8 + wid;     // 0..1023, rows 2w,2w+1
    const int r0  = 2*w, r1 = r0 + 1;
    const int hslot = (w >> 1)*CH + (w & 1)*2;
    const bool attn = ((w & 1) == 0);         // even waves own attn row s_row = w>>1
    const int s_row = w >> 1;
    const int aslot = (s_row >> 2)*CH + (s_row & 3);   // 4B word in dp/e 16B chunk

    f32x4 wh0[8], wh1[8], wa[8], wc0[2], wc1[2], ep[2], va[2];
    #pragma unroll
    for (int k = 0; k < 8; ++k) {
        wh0[k] = *(const f32x4*)(W_dec + (size_t)r0*(V+2*H) + V + H + 4*(lane + 64*k));
        wh1[k] = *(const f32x4*)(W_dec + (size_t)r1*(V+2*H) + V + H + 4*(lane + 64*k));
        wa[k]  = (f32x4)(0.f);
    }
    #pragma unroll
    for (int k = 0; k < 2; ++k) {
        wc0[k] = *(const f32x4*)(WcT + (size_t)r0*S + 4*(lane + 64*k));
        wc1[k] = *(const f32x4*)(WcT + (size_t)r1*S + 4*(lane + 64*k));
        ep[k] = (f32x4)(0.f); va[k] = (f32x4)(0.f);
    }
    if (attn) {
        #pragma unroll
        for (int k = 0; k < 8; ++k)
            wa[k] = *(const f32x4*)(Wa_dec + (size_t)s_row*H + 4*(lane + 64*k));
        #pragma unroll
        for (int k = 0; k < 2; ++k) {
            ep[k] = *(const f32x4*)(enc_proj + (size_t)s_row*A + 4*(lane + 64*k));
            va[k] = *(const f32x4*)(v_a + 4*(lane + 64*k));
        }
    }
    const f32x4* ps4 = (const f32x4*)ps;
    const f32x4* es4 = (const f32x4*)es;

    for (int t = 0; t < S; ++t) {
        const int ph  = t % 3;
        const int phn = (t+1) % 3;
        const int php = (t+2) % 3;   // == (t-1)%3

        float ax0 = accx[(size_t)t*H + r0];   // broadcast loads, all lanes
        float ax1 = accx[(size_t)t*H + r1];

        // ---- A: stage h_{t-1} (double-buffered) ----
        if (t == 0) ((f32x4*)hs[0])[tid] = ((const f32x4*)(enc_states + (size_t)(S-1)*H))[tid];
        else        ((f32x4*)hs[t&1])[tid] = poll4(hexd + php*HPH + tid*CH);
        __syncthreads();                                   // sync1

        // resets (proven-consumed phases; drain during compute)
        if (lane == 0) st_rst2(hexd + phn*HPH + hslot);
        if (t > 0 && attn && lane == 0) {
            st_rst1(dpex + php*DPH + aslot);
            st_rst1(eex  + php*DPH + aslot);
        }

        const f32x4* h4 = (const f32x4*)hs[t&1];

        // ---- B: attn waves publish dec_proj word ASAP (atomic), then all W_h dots ----
        if (attn) {
            float aP = 0.f;
            #pragma unroll
            for (int k = 0; k < 8; ++k) {
                f32x4 hv = h4[lane + 64*k];
                aP += wa[k].x*hv.x + wa[k].y*hv.y + wa[k].z*hv.z + wa[k].w*hv.w;
            }
            #pragma unroll
            for (int off = 32; off; off >>= 1) aP += __shfl_down(aP, off);
            if (lane == 0) {
                vm_drain();
                ax_st32((unsigned*)(dpex + ph*DPH + aslot), __float_as_uint(aP));
            }
        }
        float aH0 = 0.f, aH1 = 0.f;
        #pragma unroll
        for (int k = 0; k < 8; ++k) {
            f32x4 hv = h4[lane + 64*k];
            aH0 += wh0[k].x*hv.x + wh0[k].y*hv.y + wh0[k].z*hv.z + wh0[k].w*hv.w;
            aH1 += wh1[k].x*hv.x + wh1[k].y*hv.y + wh1[k].z*hv.z + wh1[k].w*hv.w;
        }
        #pragma unroll
        for (int off = 32; off; off >>= 1) { aH0 += __shfl_down(aH0, off); aH1 += __shfl_down(aH1, off); }

        // ---- C: threads 0..127 poll dp chunks; attn waves compute+publish e (atomic) ----
        if (tid < 128) ((f32x4*)ps)[tid] = poll4(dpex + ph*DPH + tid*CH);
        __syncthreads();                                   // sync2
        if (attn) {
            float e_ = 0.f;
            #pragma unroll
            for (int k = 0; k < 2; ++k) {
                f32x4 p = ps4[lane + 64*k];
                e_ += va[k].x*tanhf(ep[k].x + p.x) + va[k].y*tanhf(ep[k].y + p.y)
                    + va[k].z*tanhf(ep[k].z + p.z) + va[k].w*tanhf(ep[k].w + p.w);
            }
            #pragma unroll
            for (int off = 32; off; off >>= 1) e_ += __shfl_down(e_, off);
            if (lane == 0) {
                vm_drain();
                ax_st32((unsigned*)(eex + ph*DPH + aslot), __float_as_uint(expf(e_)));
            }
        }

        // ---- D: threads 0..127 poll e chunks ----
        if (tid < 128) ((f32x4*)es)[tid] = poll4(eex + ph*DPH + tid*CH);
        __syncthreads();                                   // syncD

        // ---- E: Z, ctx, h_new, atomic publish ----
        float z = es[tid];
        #pragma unroll
        for (int off = 32; off; off >>= 1) z += __shfl_down(z, off);
        if (lane == 0) zred[wid] = z;
        __syncthreads();                                   // syncZ
        const float Z = zred[0]+zred[1]+zred[2]+zred[3]+zred[4]+zred[5]+zred[6]+zred[7];

        float c0 = 0.f, c1 = 0.f;
        #pragma unroll
        for (int k = 0; k < 2; ++k) {
            f32x4 ev = es4[lane + 64*k];
            c0 += wc0[k].x*ev.x + wc0[k].y*ev.y + wc0[k].z*ev.z + wc0[k].w*ev.w;
            c1 += wc1[k].x*ev.x + wc1[k].y*ev.y + wc1[k].z*ev.z + wc1[k].w*ev.w;
        }
        #pragma unroll
        for (int off = 32; off; off >>= 1) { c0 += __shfl_down(c0, off); c1 += __shfl_down(c1, off); }

        if (lane == 0) {
            const float Zi = 1.f / Z;
            float h0 = tanhf(ax0 + aH0 + c0*Zi);
            float h1 = tanhf(ax1 + aH1 + c1*Zi);
            vm_drain();                                    // resets at IC before publish
            ax_st64((u64*)(hexd + ph*HPH + hslot), pack2(h0, h1));
            f32x2 hv; hv.x = h0; hv.y = h1;                // off critical path
            *(f32x2*)(h_dec + (size_t)t*H + r0) = hv;
        }
    }
}

extern "C" void kernel_launch(void* const* d_in, const int* in_sizes, int n_in,
                              void* d_out, int out_size, void* d_ws, size_t ws_size,
                              hipStream_t stream) {
    const float* x_enc  = (const float*)d_in[0];
    const float* x_dec  = (const float*)d_in[1];
    const float* W_enc  = (const float*)d_in[2];
    const float* b_enc  = (const float*)d_in[3];
    const float* Wa_enc = (const float*)d_in[4];
    const float* Wa_dec = (const float*)d_in[5];
    const float* v_a    = (const float*)d_in[6];
    const float* W_dec  = (const float*)d_in[7];
    const float* b_dec  = (const float*)d_in[8];
    const float* W_out  = (const float*)d_in[9];
    const float* b_out  = (const float*)d_in[10];
    float* out = (float*)d_out;

    float* ws         = (float*)d_ws;
    float* accx_enc   = ws;                          // S*H
    float* enc_states = accx_enc + (size_t)S*H;      // S*H
    float* enc_proj   = enc_states + (size_t)S*H;    // S*A
    float* WcT        = enc_proj + (size_t)S*A;      // H*S
    float* accx_dec   = WcT + (size_t)H*S;           // S*H
    float* h_dec      = accx_dec + (size_t)S*H;      // S*H
    float* hex_e      = h_dec + (size_t)S*H;         // 3*HPH
    float* hex_d      = hex_e + 3*HPH;               // 3*HPH
    float* dp_ex      = hex_d + 3*HPH;               // 3*DPH
    float* e_ex       = dp_ex + 3*DPH;               // 3*DPH
    const int n_ex = 3*HPH*2 + 3*DPH*2;

    dim3 b256(256);

    init_ex<<<dim3((n_ex + 255)/256), b256, 0, stream>>>((unsigned*)hex_e, n_ex);

    // accx_enc = x_enc @ W_enc[:, :V].T + b_enc
    gemm_nt<<<dim3(H/64, S/64), b256, 0, stream>>>(x_enc, V, W_enc, V+H, accx_enc, H, b_enc, S, H, V);
    // accx_dec = x_dec @ W_dec[:, :V].T + b_dec
    gemm_nt<<<dim3(H/64, S/64), b256, 0, stream>>>(x_dec, V, W_dec, V+2*H, accx_dec, H, b_dec, S, H, V);

    // encoder scan
    {
        const float* We = W_enc; const float* ax = accx_enc; float* st = enc_states; float* hx = hex_e;
        void* args[] = { &We, &ax, &st, &hx };
        hipLaunchCooperativeKernel((void*)enc_scan, dim3(NBLK), dim3(NTHR), args, 0, stream);
    }

    // enc_proj = enc_states @ Wa_enc.T
    gemm_nt<<<dim3(A/64, S/64), b256, 0, stream>>>(enc_states, H, Wa_enc, H, enc_proj, A, nullptr, S, A, H);
    // WcT[i][s] = W_c[i]·enc_states[s]
    gemm_nt<<<dim3(S/64, H/64), b256, 0, stream>>>(W_dec + V, V+2*H, enc_states, H, WcT, S, nullptr, H, S, H);

    // decoder scan
    {
        const float* wa = Wa_dec; const float* wd = W_dec; const float* epj = enc_proj;
        const float* vv = v_a; const float* wc = WcT; const float* ax = accx_dec;
        const float* est = enc_states; float* hd = h_dec;
        float* hx = hex_d; float* dx = dp_ex; float* ex = e_ex;
        void* args[] = { &wa, &wd, &epj, &vv, &wc, &ax, &est, &hd, &hx, &dx, &ex };
        hipLaunchCooperativeKernel((void*)dec_scan, dim3(NBLK), dim3(NTHR), args, 0, stream);
    }

    // logits = h_dec @ W_out.T + b_out
    gemm_nt<<<dim3(V/64, S/64), b256, 0, stream>>>(h_dec, H, W_out, H, out, V, b_out, S, V, H);
}

// Round 12
// 6387.100 us; speedup vs baseline: 1.0690x; 1.0690x over previous
//
#include <hip/hip_runtime.h>

#define V 256
#define H 2048
#define A 512
#define S 512
#define NBLK 128
#define NTHR 512
#define CH 64            // floats per chunk slot (256B spread)
#define HPH (512*CH)     // h-exchange floats per phase (512 x 16B chunks)
#define DPH (128*CH)     // dp/e-exchange floats per phase (128 x 16B chunks)
#define SENTU 0x7FC00000u
#define SENT64 0x7FC000007FC00000ULL

typedef float f32x4 __attribute__((ext_vector_type(4)));
typedef float f32x2 __attribute__((ext_vector_type(2)));
typedef unsigned long long u64;

// ---- plain coherent poll side (NaN-sentinel self-tagging) ----
__device__ __forceinline__ f32x4 ld_cg4(const float* p) {
    f32x4 r;
    asm volatile("global_load_dwordx4 %0, %1, off sc0 sc1\n\ts_waitcnt vmcnt(0)"
                 : "=&v"(r) : "v"(p) : "memory");
    return r;
}
__device__ __forceinline__ f32x4 poll4(const float* p) {
    f32x4 r = ld_cg4(p);
    while (__float_as_uint(r.x) == SENTU || __float_as_uint(r.y) == SENTU ||
           __float_as_uint(r.z) == SENTU || __float_as_uint(r.w) == SENTU)
        r = ld_cg4(p);
    return r;
}

// ---- plain publish (dec): drain prior resets, then write-through store ----
__device__ __forceinline__ void st_pub2(float* p, float x, float y) {
    f32x2 v; v.x = x; v.y = y;
    asm volatile("s_waitcnt vmcnt(0)\n\tglobal_store_dwordx2 %0, %1, off sc0 sc1"
                 :: "v"(p), "v"(v) : "memory");
}
__device__ __forceinline__ void st_pub1(float* p, float x) {
    asm volatile("s_waitcnt vmcnt(0)\n\tglobal_store_dword %0, %1, off sc0 sc1"
                 :: "v"(p), "v"(x) : "memory");
}
// ---- atomic publish (enc): exchange executes at the IC coherence point ----
__device__ __forceinline__ void vm_drain() { asm volatile("s_waitcnt vmcnt(0)" ::: "memory"); }
__device__ __forceinline__ void ax_st64(u64* p, u64 v) {
    (void)__hip_atomic_exchange(p, v, __ATOMIC_RELAXED, __HIP_MEMORY_SCOPE_AGENT);
}
__device__ __forceinline__ u64 pack2(float a, float b) {
    return ((u64)__float_as_uint(b) << 32) | (u64)__float_as_uint(a);
}
// ---- plain resets (2-step slack; ordered into next publish by its vmcnt drain) ----
__device__ __forceinline__ void st_rst2(float* p) {
    f32x2 v; v.x = __uint_as_float(SENTU); v.y = __uint_as_float(SENTU);
    asm volatile("global_store_dwordx2 %0, %1, off sc0 sc1" :: "v"(p), "v"(v) : "memory");
}
__device__ __forceinline__ void st_rst1(float* p) {
    float v = __uint_as_float(SENTU);
    asm volatile("global_store_dword %0, %1, off sc0 sc1" :: "v"(p), "v"(v) : "memory");
}

__global__ void init_ex(unsigned* p, int n) {
    int i = blockIdx.x * blockDim.x + threadIdx.x;
    if (i < n) p[i] = SENTU;
}

// ---------------- generic NT GEMM (enc_proj, logits) ----------------
__global__ __launch_bounds__(256) void gemm_nt(
    const float* __restrict__ Amat, int lda,
    const float* __restrict__ Bmat, int ldb,
    float* __restrict__ C, int ldc,
    const float* __restrict__ bias, int M, int N, int K)
{
    __shared__ float As[16][68];
    __shared__ float Bs[16][68];
    const int tid = threadIdx.x;
    const int tx = tid & 15;
    const int ty = tid >> 4;
    const int m0 = blockIdx.y * 64;
    const int n0 = blockIdx.x * 64;
    const int lr = tid >> 2;
    const int lk = (tid & 3) * 4;

    float acc[4][4] = {};
    for (int k0 = 0; k0 < K; k0 += 16) {
        float4 av = *(const float4*)(Amat + (size_t)(m0 + lr) * lda + k0 + lk);
        float4 bv = *(const float4*)(Bmat + (size_t)(n0 + lr) * ldb + k0 + lk);
        __syncthreads();
        As[lk+0][lr] = av.x; As[lk+1][lr] = av.y; As[lk+2][lr] = av.z; As[lk+3][lr] = av.w;
        Bs[lk+0][lr] = bv.x; Bs[lk+1][lr] = bv.y; Bs[lk+2][lr] = bv.z; Bs[lk+3][lr] = bv.w;
        __syncthreads();
        #pragma unroll
        for (int k = 0; k < 16; ++k) {
            float a4[4], b4[4];
            #pragma unroll
            for (int i = 0; i < 4; ++i) a4[i] = As[k][ty*4+i];
            #pragma unroll
            for (int j = 0; j < 4; ++j) b4[j] = Bs[k][tx*4+j];
            #pragma unroll
            for (int i = 0; i < 4; ++i)
                #pragma unroll
                for (int j = 0; j < 4; ++j) acc[i][j] += a4[i] * b4[j];
        }
    }
    #pragma unroll
    for (int i = 0; i < 4; ++i) {
        const int m = m0 + ty*4 + i;
        #pragma unroll
        for (int j = 0; j < 4; ++j) {
            const int n = n0 + tx*4 + j;
            float v = acc[i][j];
            if (bias) v += bias[n];
            C[(size_t)m * ldc + n] = v;
        }
    }
}

// ---------------- persistent encoder scan: atomic publish + folded x-projection ----------------
__global__ __launch_bounds__(NTHR, 2) void enc_scan(
    const float* __restrict__ W_enc, const float* __restrict__ x_enc,
    const float* __restrict__ b_enc,
    float* __restrict__ states, float* __restrict__ hex)
{
    __shared__ __align__(16) float hs[2][H];
    __shared__ __align__(16) float xs[2][V];
    const int tid = threadIdx.x;
    const int wid = tid >> 6, lane = tid & 63;
    const int w   = blockIdx.x * 8 + wid;     // 0..1023, rows 2w,2w+1
    const int r0  = 2*w, r1 = r0 + 1;
    const int slot = (w >> 1)*CH + (w & 1)*2;

    f32x4 we0[8], we1[8];
    #pragma unroll
    for (int k = 0; k < 8; ++k) {
        we0[k] = *(const f32x4*)(W_enc + (size_t)r0*(V+H) + V + 4*(lane + 64*k));
        we1[k] = *(const f32x4*)(W_enc + (size_t)r1*(V+H) + V + 4*(lane + 64*k));
    }
    const f32x4 wx0 = *(const f32x4*)(W_enc + (size_t)r0*(V+H) + 4*lane);
    const f32x4 wx1 = *(const f32x4*)(W_enc + (size_t)r1*(V+H) + 4*lane);
    const float bb0 = b_enc[r0], bb1 = b_enc[r1];

    // t = 0: h = tanh(Wx x_0 + b)
    if (tid < 64) ((f32x4*)xs[0])[tid] = ((const f32x4*)x_enc)[tid];
    __syncthreads();
    {
        f32x4 xv = ((const f32x4*)xs[0])[lane];
        float a0 = wx0.x*xv.x + wx0.y*xv.y + wx0.z*xv.z + wx0.w*xv.w;
        float a1 = wx1.x*xv.x + wx1.y*xv.y + wx1.z*xv.z + wx1.w*xv.w;
        #pragma unroll
        for (int off = 32; off; off >>= 1) { a0 += __shfl_down(a0, off); a1 += __shfl_down(a1, off); }
        if (lane == 0) {
            float h0 = tanhf(a0 + bb0), h1 = tanhf(a1 + bb1);
            vm_drain();
            ax_st64((u64*)(hex + 0*HPH + slot), pack2(h0, h1));
            states[r0] = h0; states[r1] = h1;
        }
    }

    for (int t = 1; t < S; ++t) {
        if (tid < 64) ((f32x4*)xs[t&1])[tid] = ((const f32x4*)(x_enc + (size_t)t*V))[tid];
        ((f32x4*)hs[t&1])[tid] = poll4(hex + ((t-1)%3)*HPH + tid*CH);
        __syncthreads();
        if (lane == 0) st_rst2(hex + ((t+1)%3)*HPH + slot);

        f32x4 xv = ((const f32x4*)xs[t&1])[lane];
        float a0 = wx0.x*xv.x + wx0.y*xv.y + wx0.z*xv.z + wx0.w*xv.w;
        float a1 = wx1.x*xv.x + wx1.y*xv.y + wx1.z*xv.z + wx1.w*xv.w;
        const f32x4* h4 = (const f32x4*)hs[t&1];
        #pragma unroll
        for (int k = 0; k < 8; ++k) {
            f32x4 hv = h4[lane + 64*k];
            a0 += we0[k].x*hv.x + we0[k].y*hv.y + we0[k].z*hv.z + we0[k].w*hv.w;
            a1 += we1[k].x*hv.x + we1[k].y*hv.y + we1[k].z*hv.z + we1[k].w*hv.w;
        }
        #pragma unroll
        for (int off = 32; off; off >>= 1) { a0 += __shfl_down(a0, off); a1 += __shfl_down(a1, off); }
        if (lane == 0) {
            float h0 = tanhf(a0 + bb0), h1 = tanhf(a1 + bb1);
            vm_drain();
            ax_st64((u64*)(hex + (t%3)*HPH + slot), pack2(h0, h1));
            states[(size_t)t*H + r0] = h0;
            states[(size_t)t*H + r1] = h1;
        }
    }
}

// ---------------- persistent decoder scan: R7 comm structure + folded x + WcT preload ----------------
__global__ __launch_bounds__(NTHR, 2) void dec_scan(
    const float* __restrict__ Wa_dec, const float* __restrict__ W_dec,
    const float* __restrict__ enc_proj, const float* __restrict__ v_a,
    const float* __restrict__ x_dec, const float* __restrict__ b_dec,
    const float* __restrict__ enc_states, float* __restrict__ h_dec,
    float* __restrict__ hexd, float* __restrict__ dpex, float* __restrict__ eex)
{
    __shared__ __align__(16) float hs[2][H];
    __shared__ __align__(16) float ps[A];
    __shared__ __align__(16) float es[S];
    __shared__ __align__(16) float xs[2][V];
    __shared__ __align__(16) float wct[8][2][S];   // 32 KB preload scratch
    __shared__ float zred[8];
    const int tid = threadIdx.x;
    const int wid = tid >> 6, lane = tid & 63;
    const int w   = blockIdx.x * 8 + wid;     // 0..1023, rows 2w,2w+1
    const int r0  = 2*w, r1 = r0 + 1;
    const int hslot = (w >> 1)*CH + (w & 1)*2;
    const bool attn = ((w & 1) == 0);         // even waves own attn row s_row = w>>1
    const int s_row = w >> 1;
    const int aslot = (s_row >> 2)*CH + (s_row & 3);

    // ---- preload: wc rows = (W_c rows r0,r1) · enc_states[s], s = 0..S-1 ----
    f32x4 wc0[2], wc1[2];
    {
        f32x4 wcr0[8], wcr1[8];
        #pragma unroll
        for (int k = 0; k < 8; ++k) {
            wcr0[k] = *(const f32x4*)(W_dec + (size_t)r0*(V+2*H) + V + 4*(lane + 64*k));
            wcr1[k] = *(const f32x4*)(W_dec + (size_t)r1*(V+2*H) + V + 4*(lane + 64*k));
        }
        for (int s = 0; s < S; ++s) {
            ((f32x4*)hs[s&1])[tid] = ((const f32x4*)(enc_states + (size_t)s*H))[tid];
            __syncthreads();
            const f32x4* h4 = (const f32x4*)hs[s&1];
            float p0 = 0.f, p1 = 0.f;
            #pragma unroll
            for (int k = 0; k < 8; ++k) {
                f32x4 hv = h4[lane + 64*k];
                p0 += wcr0[k].x*hv.x + wcr0[k].y*hv.y + wcr0[k].z*hv.z + wcr0[k].w*hv.w;
                p1 += wcr1[k].x*hv.x + wcr1[k].y*hv.y + wcr1[k].z*hv.z + wcr1[k].w*hv.w;
            }
            #pragma unroll
            for (int off = 32; off; off >>= 1) { p0 += __shfl_down(p0, off); p1 += __shfl_down(p1, off); }
            if (lane == 0) { wct[wid][0][s] = p0; wct[wid][1][s] = p1; }
        }
        __syncthreads();
        #pragma unroll
        for (int k = 0; k < 2; ++k) {
            wc0[k] = *(const f32x4*)(&wct[wid][0][4*(lane + 64*k)]);
            wc1[k] = *(const f32x4*)(&wct[wid][1][4*(lane + 64*k)]);
        }
        __syncthreads();
    }

    // ---- remaining register-resident weights ----
    f32x4 wh0[8], wh1[8], wa[8], ep[2], va[2];
    #pragma unroll
    for (int k = 0; k < 8; ++k) {
        wh0[k] = *(const f32x4*)(W_dec + (size_t)r0*(V+2*H) + V + H + 4*(lane + 64*k));
        wh1[k] = *(const f32x4*)(W_dec + (size_t)r1*(V+2*H) + V + H + 4*(lane + 64*k));
        wa[k]  = (f32x4)(0.f);
    }
    #pragma unroll
    for (int k = 0; k < 2; ++k) { ep[k] = (f32x4)(0.f); va[k] = (f32x4)(0.f); }
    if (attn) {
        #pragma unroll
        for (int k = 0; k < 8; ++k)
            wa[k] = *(const f32x4*)(Wa_dec + (size_t)s_row*H + 4*(lane + 64*k));
        #pragma unroll
        for (int k = 0; k < 2; ++k) {
            ep[k] = *(const f32x4*)(enc_proj + (size_t)s_row*A + 4*(lane + 64*k));
            va[k] = *(const f32x4*)(v_a + 4*(lane + 64*k));
        }
    }
    const f32x4 wx0 = *(const f32x4*)(W_dec + (size_t)r0*(V+2*H) + 4*lane);
    const f32x4 wx1 = *(const f32x4*)(W_dec + (size_t)r1*(V+2*H) + 4*lane);
    const float bb0 = b_dec[r0], bb1 = b_dec[r1];

    const f32x4* ps4 = (const f32x4*)ps;
    const f32x4* es4 = (const f32x4*)es;

    for (int t = 0; t < S; ++t) {
        const int ph  = t % 3;
        const int phn = (t+1) % 3;
        const int php = (t+2) % 3;   // == (t-1)%3

        // stage x_dec[t] (read at phase E; double-buffered)
        if (tid < 64) ((f32x4*)xs[t&1])[tid] = ((const f32x4*)(x_dec + (size_t)t*V))[tid];

        // ---- A: stage h_{t-1} ----
        if (t == 0) ((f32x4*)hs[0])[tid] = ((const f32x4*)(enc_states + (size_t)(S-1)*H))[tid];
        else        ((f32x4*)hs[t&1])[tid] = poll4(hexd + php*HPH + tid*CH);
        __syncthreads();                                   // sync1

        // resets (proven-consumed phases; drain into the next publish)
        if (lane == 0) st_rst2(hexd + phn*HPH + hslot);
        if (t > 0 && attn && lane == 0) {
            st_rst1(dpex + php*DPH + aslot);
            st_rst1(eex  + php*DPH + aslot);
        }

        const f32x4* h4 = (const f32x4*)hs[t&1];

        // ---- B: attn waves publish dec_proj word ASAP, then all W_h (+Wx) dots ----
        if (attn) {
            float aP = 0.f;
            #pragma unroll
            for (int k = 0; k < 8; ++k) {
                f32x4 hv = h4[lane + 64*k];
                aP += wa[k].x*hv.x + wa[k].y*hv.y + wa[k].z*hv.z + wa[k].w*hv.w;
            }
            #pragma unroll
            for (int off = 32; off; off >>= 1) aP += __shfl_down(aP, off);
            if (lane == 0) st_pub1(dpex + ph*DPH + aslot, aP);
        }
        f32x4 xv = ((const f32x4*)xs[t&1])[lane];
        float aH0 = wx0.x*xv.x + wx0.y*xv.y + wx0.z*xv.z + wx0.w*xv.w;
        float aH1 = wx1.x*xv.x + wx1.y*xv.y + wx1.z*xv.z + wx1.w*xv.w;
        #pragma unroll
        for (int k = 0; k < 8; ++k) {
            f32x4 hv = h4[lane + 64*k];
            aH0 += wh0[k].x*hv.x + wh0[k].y*hv.y + wh0[k].z*hv.z + wh0[k].w*hv.w;
            aH1 += wh1[k].x*hv.x + wh1[k].y*hv.y + wh1[k].z*hv.z + wh1[k].w*hv.w;
        }
        #pragma unroll
        for (int off = 32; off; off >>= 1) { aH0 += __shfl_down(aH0, off); aH1 += __shfl_down(aH1, off); }

        // ---- C: threads 0..127 poll dp chunks; attn waves compute+publish e ----
        if (tid < 128) ((f32x4*)ps)[tid] = poll4(dpex + ph*DPH + tid*CH);
        __syncthreads();                                   // sync2
        if (attn) {
            float e_ = 0.f;
            #pragma unroll
            for (int k = 0; k < 2; ++k) {
                f32x4 p = ps4[lane + 64*k];
                e_ += va[k].x*tanhf(ep[k].x + p.x) + va[k].y*tanhf(ep[k].y + p.y)
                    + va[k].z*tanhf(ep[k].z + p.z) + va[k].w*tanhf(ep[k].w + p.w);
            }
            #pragma unroll
            for (int off = 32; off; off >>= 1) e_ += __shfl_down(e_, off);
            if (lane == 0) st_pub1(eex + ph*DPH + aslot, expf(e_));
        }

        // ---- D: threads 0..127 poll e chunks ----
        if (tid < 128) ((f32x4*)es)[tid] = poll4(eex + ph*DPH + tid*CH);
        __syncthreads();                                   // syncD

        // ---- E: Z, ctx, h_new, publish ----
        float z = es[tid];
        #pragma unroll
        for (int off = 32; off; off >>= 1) z += __shfl_down(z, off);
        if (lane == 0) zred[wid] = z;
        __syncthreads();                                   // syncZ
        const float Z = zred[0]+zred[1]+zred[2]+zred[3]+zred[4]+zred[5]+zred[6]+zred[7];

        float c0 = 0.f, c1 = 0.f;
        #pragma unroll
        for (int k = 0; k < 2; ++k) {
            f32x4 ev = es4[lane + 64*k];
            c0 += wc0[k].x*ev.x + wc0[k].y*ev.y + wc0[k].z*ev.z + wc0[k].w*ev.w;
            c1 += wc1[k].x*ev.x + wc1[k].y*ev.y + wc1[k].z*ev.z + wc1[k].w*ev.w;
        }
        #pragma unroll
        for (int off = 32; off; off >>= 1) { c0 += __shfl_down(c0, off); c1 += __shfl_down(c1, off); }

        if (lane == 0) {
            const float Zi = 1.f / Z;
            float h0 = tanhf(aH0 + bb0 + c0*Zi);
            float h1 = tanhf(aH1 + bb1 + c1*Zi);
            st_pub2(hexd + ph*HPH + hslot, h0, h1);        // vmcnt drain orders resets
            f32x2 hv; hv.x = h0; hv.y = h1;                // off critical path
            *(f32x2*)(h_dec + (size_t)t*H + r0) = hv;
        }
    }
}

extern "C" void kernel_launch(void* const* d_in, const int* in_sizes, int n_in,
                              void* d_out, int out_size, void* d_ws, size_t ws_size,
                              hipStream_t stream) {
    const float* x_enc  = (const float*)d_in[0];
    const float* x_dec  = (const float*)d_in[1];
    const float* W_enc  = (const float*)d_in[2];
    const float* b_enc  = (const float*)d_in[3];
    const float* Wa_enc = (const float*)d_in[4];
    const float* Wa_dec = (const float*)d_in[5];
    const float* v_a    = (const float*)d_in[6];
    const float* W_dec  = (const float*)d_in[7];
    const float* b_dec  = (const float*)d_in[8];
    const float* W_out  = (const float*)d_in[9];
    const float* b_out  = (const float*)d_in[10];
    float* out = (float*)d_out;

    float* ws         = (float*)d_ws;
    float* enc_states = ws;                          // S*H
    float* enc_proj   = enc_states + (size_t)S*H;    // S*A
    float* h_dec      = enc_proj + (size_t)S*A;      // S*H
    float* hex_e      = h_dec + (size_t)S*H;         // 3*HPH
    float* hex_d      = hex_e + 3*HPH;               // 3*HPH
    float* dp_ex      = hex_d + 3*HPH;               // 3*DPH
    float* e_ex       = dp_ex + 3*DPH;               // 3*DPH
    const int n_ex = 3*HPH*2 + 3*DPH*2;

    dim3 b256(256);

    init_ex<<<dim3((n_ex + 255)/256), b256, 0, stream>>>((unsigned*)hex_e, n_ex);

    // encoder scan (x-projection folded; no accx GEMM)
    {
        const float* We = W_enc; const float* xe = x_enc; const float* be = b_enc;
        float* st = enc_states; float* hx = hex_e;
        void* args[] = { &We, &xe, &be, &st, &hx };
        hipLaunchCooperativeKernel((void*)enc_scan, dim3(NBLK), dim3(NTHR), args, 0, stream);
    }

    // enc_proj = enc_states @ Wa_enc.T
    gemm_nt<<<dim3(A/64, S/64), b256, 0, stream>>>(enc_states, H, Wa_enc, H, enc_proj, A, nullptr, S, A, H);

    // decoder scan (x-projection + WcT folded; no accx/WcT GEMMs)
    {
        const float* wa = Wa_dec; const float* wd = W_dec; const float* epj = enc_proj;
        const float* vv = v_a; const float* xd = x_dec; const float* bd = b_dec;
        const float* est = enc_states; float* hd = h_dec;
        float* hx = hex_d; float* dx = dp_ex; float* ex = e_ex;
        void* args[] = { &wa, &wd, &epj, &vv, &xd, &bd, &est, &hd, &hx, &dx, &ex };
        hipLaunchCooperativeKernel((void*)dec_scan, dim3(NBLK), dim3(NTHR), args, 0, stream);
    }

    // logits = h_dec @ W_out.T + b_out
    gemm_nt<<<dim3(V/64, S/64), b256, 0, stream>>>(h_dec, H, W_out, H, out, V, b_out, S, V, H);
}